// Round 6
// baseline (266.407 us; speedup 1.0000x reference)
//
#include <hip/hip_runtime.h>
#include <hip/hip_bf16.h>

// ---------- helpers ----------

typedef __attribute__((ext_vector_type(8))) short bf16x8;
typedef __attribute__((ext_vector_type(4))) float f32x4;

#define AS_G(p) ((__attribute__((address_space(1))) void*)(p))
#define AS_L(p) ((__attribute__((address_space(3))) void*)(p))

__device__ __forceinline__ unsigned short f2bf(float f) {
  unsigned int u = __float_as_uint(f);
  unsigned int lsb = (u >> 16) & 1u;
  u += 0x7fffu + lsb;
  return (unsigned short)(u >> 16);
}

#define WAITV(n) asm volatile("s_waitcnt vmcnt(" #n ")" ::: "memory")
#define BARRIER() do { asm volatile("" ::: "memory");                         \
    __builtin_amdgcn_s_barrier();                                             \
    asm volatile("" ::: "memory");                                            \
    __builtin_amdgcn_sched_barrier(0); } while (0)

// ---------- 256xBN 2-region NT GEMM, counted vmcnt, PERSISTENT tiles ----------
// R5 post-mortem: MI=4 geometry is +8% per-FLOP over MI=8; proj still paid a
// 0.75 duty factor (384 blocks = 1.5 rounds at 1 block/CU). R6: persistent
// blocks -- launch exactly 256 blocks, each runs TILES equal tiles in
// sequence (exact duty, no partial rounds). Tile mapping shares the A-panel
// across a block's tiles (L2 reuse):
//   TILES=3 (proj): y=b>>3, x=(b&7)+8*it  (768 tiles; it == q/k/v segment)
//   TILES=2 (QK):   z=b>>6, y=(b&63)>>3, x=(b&7)+8*it  (512 tiles)
//   TILES=1 (PV):   3D grid as before (256 blocks, control dispatch)
//
// Geometry MI=4: BM=256, BN=128, 8 waves 4M x 2N, per-wave 64x64, acc[4][4],
// LDS 2 x 48K = 96K. (MI=8: BM=BN=256, 2M x 4N, acc[8][4], 128K -- unused
// this round but kept.)
// Swizzle (measured 0 SQ_LDS_BANK_CONFLICT): LDS row = 8 chunks of 8 elems
// (16B); slot s of row r holds k-chunk s ^ (r&7); staging pre-swizzles the
// GLOBAL source so the LDS dest stays linear (global_load_lds requirement).
//
// Two regions per K-tile; ds_reads issued at region top service under the
// MFMA cluster; counted vmcnt never reaches 0 in steady state (m218).
// MI=4 staging (6 loads/tile): carry B q0,q1 in R1 (other buf), lead
// A q0..q3 in R2 (this buf); tile-end vmcnt(4); prologue vmcnt(6).
// WAR/RAW audit: every staged block's readers passed a barrier before the
// stage issues; buffer completeness guaranteed by the previous tile's
// counted wait (loads complete oldest-first, m135). Persistent tile loop:
// epilogue touches no LDS, final KTILE ends WAITV(0)+BARRIER -> next tile's
// prologue staging is race-free.
//
// EPI=1: QK: P' = bf16(exp(acc*scale)) (unnormalized softmax numerator;
//        |acc*scale| small by construction) + fp32 atomic row-sum to rsum.
// EPI=2: proj split: col seg 0 -> qb (+bq), seg 1 -> kb (+bk), seg 2 -> vt
//        TRANSPOSED (+bv) as ushort4.
// EPI=3: PV: out fp32 = acc / rsum[row].

// stage one 64-row block (1 global_load_lds per thread, 512thr x 16B = 8KB)
#define S64A(ktk, rb, bofs)                                                   \
  __builtin_amdgcn_global_load_lds(                                           \
      AS_G(A + (size_t)(rowBase + (rb) * 64 + r0) * lda + (ktk) + goff),      \
      AS_L(lds + (bofs) + (rb) * 4096 + t * 8), 16, 0, 0)

#define S64B(ktk, rb, bofs)                                                   \
  __builtin_amdgcn_global_load_lds(                                           \
      AS_G(B + (size_t)(colBase + (rb) * 64 + r0) * ldb + (ktk) + goff),      \
      AS_L(lds + (bofs) + 16384 + (rb) * 4096 + t * 8), 16, 0, 0)

// A-frag loads: MI=8 reads half ih (4 frags), MI=4 reads all 4 frags.
#define LOADA8(ih, bofs) do { _Pragma("unroll")                               \
    for (int ks_ = 0; ks_ < 2; ks_++) { _Pragma("unroll")                     \
      for (int ii = 0; ii < 4; ii++) {                                        \
        int row_ = wrow + ((ih) * 4 + ii) * 16 + r16;                         \
        int slot_ = (ks_ * 4 + q) ^ (r16 & 7);                                \
        af[ks_][ii] = *(const bf16x8*)(lds + (bofs) + row_ * 64 + slot_ * 8); \
      } } } while (0)

#define LOADA4(bofs) do { _Pragma("unroll")                                   \
    for (int ks_ = 0; ks_ < 2; ks_++) { _Pragma("unroll")                     \
      for (int ii = 0; ii < 4; ii++) {                                        \
        int row_ = wrow + ii * 16 + r16;                                      \
        int slot_ = (ks_ * 4 + q) ^ (r16 & 7);                                \
        af[ks_][ii] = *(const bf16x8*)(lds + (bofs) + row_ * 64 + slot_ * 8); \
      } } } while (0)

#define LOADB(jh, bofs) do { _Pragma("unroll")                                \
    for (int ks_ = 0; ks_ < 2; ks_++) { _Pragma("unroll")                     \
      for (int jj = 0; jj < 2; jj++) {                                        \
        int row_ = wcol + ((jh) * 2 + jj) * 16 + r16;                         \
        int slot_ = (ks_ * 4 + q) ^ (r16 & 7);                                \
        bfr[ks_][(jh) * 2 + jj] =                                             \
            *(const bf16x8*)(lds + (bofs) + 16384 + row_ * 64 + slot_ * 8);   \
      } } } while (0)

// MFMA cluster over acc rows ihb..ihb+3, cols j0..j1 (per-element
// accumulation order: ks0 then ks1 -- unchanged across rounds).
#define MMQ(ihb, j0, j1) do { __builtin_amdgcn_s_setprio(1); _Pragma("unroll")\
    for (int ks_ = 0; ks_ < 2; ks_++) { _Pragma("unroll")                     \
      for (int ii = 0; ii < 4; ii++) { _Pragma("unroll")                      \
        for (int jj = (j0); jj <= (j1); jj++)                                 \
          acc[(ihb) + ii][jj] = __builtin_amdgcn_mfma_f32_16x16x32_bf16(      \
              af[ks_][ii], bfr[ks_][jj], acc[(ihb) + ii][jj], 0, 0, 0);       \
      } }                                                                     \
    __builtin_amdgcn_s_setprio(0); } while (0)

// MI=8 K-tile (8 loads: carry 2 in R1, lead 6 in R2, vmcnt(6))
#define TILE8(ktc, bofs, obofs) do {                                          \
    LOADA8(0, bofs); LOADB(0, bofs); LOADB(1, bofs);                          \
    if ((ktc) && (ktc) + 64 < K) {                                            \
      S64A((ktc) + 64, 1, obofs); S64A((ktc) + 64, 3, obofs);                 \
    }                                                                         \
    MMQ(0, 0, 3);                                                             \
    BARRIER();                                                                \
    LOADA8(1, bofs);                                                          \
    if ((ktc) + 128 < K) {                                                    \
      S64A((ktc) + 128, 0, bofs); S64A((ktc) + 128, 2, bofs);                 \
      S64B((ktc) + 128, 0, bofs); S64B((ktc) + 128, 1, bofs);                 \
      S64B((ktc) + 128, 2, bofs); S64B((ktc) + 128, 3, bofs);                 \
    }                                                                         \
    MMQ(4, 0, 3);                                                             \
    if ((ktc) + 128 < K) { WAITV(6); } else { WAITV(0); }                     \
    BARRIER(); } while (0)

// MI=4 K-tile (6 loads: carry B q0,q1 in R1, lead A q0..q3 in R2, vmcnt(4))
#define TILE4(ktc, bofs, obofs) do {                                          \
    LOADA4(bofs); LOADB(0, bofs);                                             \
    if ((ktc) && (ktc) + 64 < K) {                                            \
      S64B((ktc) + 64, 0, obofs); S64B((ktc) + 64, 1, obofs);                 \
    }                                                                         \
    MMQ(0, 0, 1);                                                             \
    BARRIER();                                                                \
    LOADB(1, bofs);                                                           \
    if ((ktc) + 128 < K) {                                                    \
      S64A((ktc) + 128, 0, bofs); S64A((ktc) + 128, 1, bofs);                 \
      S64A((ktc) + 128, 2, bofs); S64A((ktc) + 128, 3, bofs);                 \
    }                                                                         \
    MMQ(0, 2, 3);                                                             \
    if ((ktc) + 128 < K) { WAITV(4); } else { WAITV(0); }                     \
    BARRIER(); } while (0)

template <int EPI, int MI, int TILES>
__global__ __launch_bounds__(512, 2) void gemm_2r(
    const unsigned short* __restrict__ A, const unsigned short* __restrict__ B,
    float* __restrict__ Cf, long long sA, long long sB, long long sC,
    int K, int lda, int ldb, int ldc,
    unsigned short* __restrict__ u0, unsigned short* __restrict__ u1,
    unsigned short* __restrict__ u2,
    const float* __restrict__ f0, const float* __restrict__ f1,
    const float* __restrict__ f2,
    float* __restrict__ rsum, float scale)
{
  constexpr int BN = MI * 32;                 // 256 or 128
  constexpr int BUFE = 16384 + BN * 64;       // elems per LDS buffer
  __shared__ unsigned short lds[2 * BUFE];    // 128 KiB (MI=8) / 96 KiB (MI=4)

  const int t = threadIdx.x;

  // persistent tile mapping
  int tx0, tyy, tzz;
  if constexpr (TILES == 1) {
    tx0 = blockIdx.x; tyy = blockIdx.y; tzz = blockIdx.z;
  } else if constexpr (TILES == 2) {   // QK: 256 blocks, 512 tiles
    tzz = blockIdx.x >> 6;
    tyy = (blockIdx.x & 63) >> 3;
    tx0 = blockIdx.x & 7;
  } else {                              // TILES==3, proj: 256 blocks, 768 tiles
    tzz = 0;
    tyy = blockIdx.x >> 3;
    tx0 = blockIdx.x & 7;
  }
  const int rowBase = tyy * 256;
  A += (long long)tzz * sA;
  B += (long long)tzz * sB;

  const int l = t & 63;
  const int w = t >> 6;  // 0..7
  const int wrow = (MI == 8) ? (w >> 2) * 128 : (w >> 1) * 64;
  const int wcol = (MI == 8) ? (w & 3) * 64 : (w & 1) * 64;
  const int q = l >> 4;
  const int r16 = l & 15;

  // staging geometry: thread t covers row r0 = t>>3 (of a 64-row block),
  // slot t&7, global k-chunk = (t&7)^(r0&7) (pre-swizzled source).
  const int r0 = t >> 3;                        // 0..63
  const int goff = ((t & 7) ^ (r0 & 7)) << 3;

#pragma unroll 1
  for (int itile = 0; itile < TILES; ++itile) {
    const int colBase = (tx0 + 8 * itile) * BN;

    f32x4 acc[MI][4] = {};
    bf16x8 af[2][4], bfr[2][4];

    // prologue: tile0 -> buf0, tile1 -> buf1; drain tile0 only.
    S64A(0, 0, 0); S64A(0, 1, 0); S64A(0, 2, 0); S64A(0, 3, 0);
    S64B(0, 0, 0); S64B(0, 1, 0);
    if constexpr (MI == 8) { S64B(0, 2, 0); S64B(0, 3, 0); }
    S64A(64, 0, BUFE); S64A(64, 1, BUFE); S64A(64, 2, BUFE); S64A(64, 3, BUFE);
    S64B(64, 0, BUFE); S64B(64, 1, BUFE);
    if constexpr (MI == 8) { S64B(64, 2, BUFE); S64B(64, 3, BUFE); }
    if constexpr (MI == 8) { WAITV(8); } else { WAITV(6); }
    BARRIER();

    for (int kt = 0; kt < K; kt += 128) {   // K is a multiple of 128
      if constexpr (MI == 8) {
        TILE8(kt, 0, BUFE);
        TILE8(kt + 64, BUFE, 0);
      } else {
        TILE4(kt, 0, BUFE);
        TILE4(kt + 64, BUFE, 0);
      }
    }

    // epilogues: C frag layout row=(lane>>4)*4+r, col=lane&15 (m89/m91).
    // No LDS access here -> next itile's staging after the final barrier is
    // race-free.
    if (EPI == 1) {
      unsigned short* p16 = u0 + (long long)tzz * sC;
      float* rs = rsum + (long long)tzz * 2048;
#pragma unroll
      for (int i = 0; i < MI; i++) {
#pragma unroll
        for (int r = 0; r < 4; r++) {
          int row = rowBase + wrow + i * 16 + q * 4 + r;
          float rowpart = 0.f;
#pragma unroll
          for (int j = 0; j < 4; j++) {
            int col = colBase + wcol + j * 16 + r16;
            float e = __expf(acc[i][j][r] * scale);
            p16[(size_t)row * ldc + col] = f2bf(e);
            rowpart += e;
          }
#pragma unroll
          for (int m = 1; m < 16; m <<= 1) rowpart += __shfl_xor(rowpart, m);
          if (r16 == 0) atomicAdd(rs + row, rowpart);
        }
      }
    } else if (EPI == 2) {
      const int seg = colBase >> 10;  // block-uniform; == itile for TILES=3
      if (seg < 2) {
        unsigned short* dst = seg ? u1 : u0;
        const float* bias = seg ? f1 : f0;
        const int cb = colBase & 1023;
#pragma unroll
        for (int i = 0; i < MI; i++) {
#pragma unroll
          for (int r = 0; r < 4; r++) {
            int row = rowBase + wrow + i * 16 + q * 4 + r;
#pragma unroll
            for (int j = 0; j < 4; j++) {
              int col = cb + wcol + j * 16 + r16;
              dst[(size_t)row * 1024 + col] = f2bf(acc[i][j][r] + bias[col]);
            }
          }
        }
      } else {
        const int ob = colBase - 2048;
#pragma unroll
        for (int i = 0; i < MI; i++) {
          int posBase = rowBase + wrow + i * 16 + q * 4;
          int b = posBase >> 11;
          int pos = posBase & 2047;
#pragma unroll
          for (int j = 0; j < 4; j++) {
            int o = ob + wcol + j * 16 + r16;
            float bias = f2[o];
            ushort4 pk;
            pk.x = f2bf(acc[i][j][0] + bias);
            pk.y = f2bf(acc[i][j][1] + bias);
            pk.z = f2bf(acc[i][j][2] + bias);
            pk.w = f2bf(acc[i][j][3] + bias);
            *(ushort4*)(u2 + ((size_t)((b << 10) + o) * 2048 + pos)) = pk;
          }
        }
      }
    } else {  // EPI == 3
      float* C = Cf + (long long)tzz * sC;
      const float* rs = rsum + (long long)tzz * 2048;
#pragma unroll
      for (int i = 0; i < MI; i++) {
#pragma unroll
        for (int r = 0; r < 4; r++) {
          int row = rowBase + wrow + i * 16 + q * 4 + r;
          float inv = 1.0f / rs[row];
#pragma unroll
          for (int j = 0; j < 4; j++) {
            int col = colBase + wcol + j * 16 + r16;
            C[(size_t)row * ldc + col] = acc[i][j][r] * inv;
          }
        }
      }
    }
  }
}

// ---------- fp32 -> bf16 cast (vectorized) + rsum zero-fill ----------

__global__ __launch_bounds__(256) void cast_f32_to_bf16(
    const float* __restrict__ in, unsigned short* __restrict__ out, int n4,
    float* __restrict__ rzero, int nz4)
{
  int i = blockIdx.x * 256 + threadIdx.x;
  if (i < nz4) ((float4*)rzero)[i] = make_float4(0.f, 0.f, 0.f, 0.f);
  if (i >= n4) return;
  float4 v = ((const float4*)in)[i];
  ushort4 o;
  o.x = f2bf(v.x); o.y = f2bf(v.y); o.z = f2bf(v.z); o.w = f2bf(v.w);
  ((ushort4*)out)[i] = o;
}

// ---------- W transpose: WT[z][h, d] = bf16(W_z[d, h]), 1024x1024, z=0..2 ----------

__global__ __launch_bounds__(256) void wtrans(
    const float* __restrict__ Wq, const float* __restrict__ Wk,
    const float* __restrict__ Wv, unsigned short* __restrict__ WT)
{
  __shared__ float tile[32][33];
  const float* in = blockIdx.z == 0 ? Wq : (blockIdx.z == 1 ? Wk : Wv);
  unsigned short* out = WT + (size_t)blockIdx.z * 1024 * 1024;
  const int bc = blockIdx.x * 32;  // h
  const int br = blockIdx.y * 32;  // d
  const int tx = threadIdx.x;
  const int ty = threadIdx.y;
#pragma unroll
  for (int i = 0; i < 4; i++)
    tile[ty + i * 8][tx] = in[(size_t)(br + ty + i * 8) * 1024 + bc + tx];
  __syncthreads();
#pragma unroll
  for (int i = 0; i < 4; i++)
    out[(size_t)(bc + ty + i * 8) * 1024 + br + tx] = f2bf(tile[tx][ty + i * 8]);
}

// ---------- driver ----------

extern "C" void kernel_launch(void* const* d_in, const int* in_sizes, int n_in,
                              void* d_out, int out_size, void* d_ws, size_t ws_size,
                              hipStream_t stream) {
  (void)in_sizes; (void)n_in; (void)out_size;

  const float* x  = (const float*)d_in[0];
  const float* Wq = (const float*)d_in[1];
  const float* bq = (const float*)d_in[2];
  const float* Wk = (const float*)d_in[3];
  const float* bk = (const float*)d_in[4];
  const float* Wv = (const float*)d_in[5];
  const float* bv = (const float*)d_in[6];
  float* out = (float*)d_out;

  const int Nb = 4, L = 2048, D = 1024, H = 1024, O = 1024;
  const int M = Nb * L;      // 8192
  const int NQKV = 3 * H;    // 3072

  char* ws = (char*)d_ws;
  size_t off = 0;
  unsigned short* xb = (unsigned short*)(ws + off); off += (size_t)M * D * 2;
  unsigned short* qb = (unsigned short*)(ws + off); off += (size_t)M * H * 2;
  unsigned short* kb = (unsigned short*)(ws + off); off += (size_t)M * H * 2;
  unsigned short* vt = (unsigned short*)(ws + off); off += (size_t)M * O * 2;
  unsigned short* WT = (unsigned short*)(ws + off); off += (size_t)NQKV * D * 2;
  unsigned short* P  = (unsigned short*)(ws + off); off += (size_t)Nb * L * L * 2;
  float* rsum = (float*)(ws + off); off += (size_t)Nb * L * 4;
  if (ws_size < off) return;

  dim3 blk256(256);
  dim3 blk512(512);

  // x -> bf16, and zero the row-sum accumulator (ws is poisoned every call)
  cast_f32_to_bf16<<<(M * D / 4 + 255) / 256, blk256, 0, stream>>>(
      x, xb, M * D / 4, rsum, Nb * L / 4);

  // WT = concat(Wq^T, Wk^T, Wv^T) as bf16 [3072, 1024] (one launch, z=3)
  wtrans<<<dim3(32, 32, 3), dim3(32, 8), 0, stream>>>(Wq, Wk, Wv, WT);

  // fused projections: q -> qb, k -> kb, v -> vt (transposed), + biases
  // PERSISTENT: 256 blocks x 3 tiles (768 tiles = 3.0 rounds, duty ~1.0;
  // itile == output segment q/k/v; A-panel reused across a block's tiles)
  gemm_2r<2, 4, 3><<<dim3(256), blk512, 0, stream>>>(
      xb, WT, nullptr, 0, 0, 0, D, D, D, 0,
      qb, kb, vt, bq, bk, bv, nullptr, 0.f);

  // QK + exp + row-sum atomics: P'[b] = exp(q k^T * scale)
  // PERSISTENT: 256 blocks x 2 tiles (512 tiles, MI=4 geometry, duty ~1.0)
  gemm_2r<1, 4, 2><<<dim3(256), blk512, 0, stream>>>(
      qb, kb, nullptr, (long long)L * H, (long long)L * H, (long long)L * L,
      H, H, H, L,
      P, nullptr, nullptr, nullptr, nullptr, nullptr,
      rsum, 0.022097086912079608f /* 1/sqrt(2048) */);

  // out[b] = (P'[b] @ vt[b]^T) / rsum
  // MI=4 tile 256x128: grid 8x8x4 = 256 blocks = 1.0 round (control)
  gemm_2r<3, 4, 1><<<dim3(O / 128, L / 256, Nb), blk512, 0, stream>>>(
      P, vt, out, (long long)L * L, (long long)O * L, (long long)L * O,
      L, L, L, O,
      nullptr, nullptr, nullptr, nullptr, nullptr, nullptr,
      rsum, 0.f);
}

// Round 7
// 259.739 us; speedup vs baseline: 1.0257x; 1.0257x over previous
//
#include <hip/hip_runtime.h>
#include <hip/hip_bf16.h>

// ---------- helpers ----------

typedef __attribute__((ext_vector_type(8))) short bf16x8;
typedef __attribute__((ext_vector_type(4))) float f32x4;

#define AS_G(p) ((__attribute__((address_space(1))) void*)(p))
#define AS_L(p) ((__attribute__((address_space(3))) void*)(p))

__device__ __forceinline__ unsigned short f2bf(float f) {
  unsigned int u = __float_as_uint(f);
  unsigned int lsb = (u >> 16) & 1u;
  u += 0x7fffu + lsb;
  return (unsigned short)(u >> 16);
}

#define WAITV(n) asm volatile("s_waitcnt vmcnt(" #n ")" ::: "memory")
// Barrier with memory fences only (NO sched_barrier: m141 says order-pinning
// hurts; our ds_reads are C++-visible so the compiler's own fine-grained
// lgkmcnt gating before MFMA is correct and better).
#define BAR() do { asm volatile("" ::: "memory");                             \
    __builtin_amdgcn_s_barrier();                                             \
    asm volatile("" ::: "memory"); } while (0)

// ---------- 256x128 fine-phase NT GEMM, 3-buffer counted-vmcnt pipeline ----------
// Faithful port of the m201/m248 8-phase rhythm onto the measured-best MI=4
// geometry. A[m,k] lda, B[n,k] ldb, bf16, K-contiguous. BM=256, BN=128,
// BK=64. 512 threads = 8 waves (4M x 2N); per-wave 64x64 = 4x4 frags of
// 16x16x32, acc[4][4].
//
// LDS: THREE buffers x (A 256x64 = 32K + B 128x64 = 16K) = 144 KiB. Three
// buffers (not two) is what gives every tile a stage window 4 phases ahead
// of its first read -- the 2-buffer variants (R2-R6) could never age the
// loads without draining vmcnt to 0 (m218: drain-0 == 1-phase == ~27%).
//
// Per K-tile: 2 phases (ks=0,1). Phase = { 8 ds_read_b128 (A 4 + B 4 frags
// for this K-half) + 3 global_load_lds of tile t+2 -> barrier -> setprio(1)
// 16 MFMA setprio(0) -> barrier }. Reads issue BEFORE the barrier, MFMA
// consumes after: read latency is absorbed by the rendezvous. vmcnt(6) ONCE
// per K-tile at the closing barrier: drains tile t+1 (its 6 loads are 2
// tiles ~3000cyc old -> free) while tile t+2's 6 stay in flight across all
// of the next tile's barriers. Tail tiles use vmcnt(0) (nothing newer).
//
// Swizzle (measured 0 SQ_LDS_BANK_CONFLICT, rounds 0-6): LDS row = 8 chunks
// of 8 elems (16B); slot s of row r holds k-chunk s ^ (r&7); staging
// pre-swizzles the GLOBAL source so the LDS dest stays linear
// (global_load_lds requirement).
//
// WAR audit: stage of tile t+2 goes to the buffer holding t-1, whose last
// ds_reads executed 2 phase-windows (4 barriers) earlier. RAW audit: reads
// of tile t are legal because the vmcnt(6)+barrier at the end of tile t-1
// proves all waves' loads up to tile t completed (loads finish oldest-first,
// m135; the barrier publishes every wave's wait).
//
// EPI=1: QK: P' = bf16(exp(acc*scale)) (unnormalized softmax numerator;
//        |acc*scale| small by construction) + fp32 atomic row-sum to rsum.
// EPI=2: proj split: col seg 0 -> qb (+bq), seg 1 -> kb (+bk), seg 2 -> vt
//        TRANSPOSED (+bv) as ushort4.
// EPI=3: PV: out fp32 = acc / rsum[row].

#define BUFE 24576  // elems per LDS buffer: A 16384 + B 8192

// stage one 64-row block (1 global_load_lds per thread, 512thr x 16B = 8KB)
#define S64A(ktk, rb, bofs)                                                   \
  __builtin_amdgcn_global_load_lds(                                           \
      AS_G(A + (size_t)(rowBase + (rb) * 64 + r0) * lda + (ktk) + goff),      \
      AS_L(lds + (bofs) + (rb) * 4096 + t * 8), 16, 0, 0)

#define S64B(ktk, rb, bofs)                                                   \
  __builtin_amdgcn_global_load_lds(                                           \
      AS_G(B + (size_t)(colBase + (rb) * 64 + r0) * ldb + (ktk) + goff),      \
      AS_L(lds + (bofs) + 16384 + (rb) * 4096 + t * 8), 16, 0, 0)

// frag reads for one K-half (ks): A 4 frags, B 4 frags (8 x ds_read_b128)
#define LDA(bofs, ks_) do { _Pragma("unroll")                                 \
    for (int ii = 0; ii < 4; ii++) {                                          \
      int row_ = wrow + ii * 16 + r16;                                        \
      int slot_ = ((ks_) * 4 + q) ^ (r16 & 7);                                \
      af[ii] = *(const bf16x8*)(lds + (bofs) + row_ * 64 + slot_ * 8);        \
    } } while (0)

#define LDB(bofs, ks_) do { _Pragma("unroll")                                 \
    for (int jj = 0; jj < 4; jj++) {                                          \
      int row_ = wcol + jj * 16 + r16;                                        \
      int slot_ = ((ks_) * 4 + q) ^ (r16 & 7);                                \
      bfr[jj] = *(const bf16x8*)(lds + (bofs) + 16384 + row_ * 64 + slot_ * 8); \
    } } while (0)

// 16 MFMA over all 4x4 frags at the current K-half. Per-acc-element order
// across the two phases is ks0 then ks1 -- identical to all prior rounds.
#define MMK() do { __builtin_amdgcn_s_setprio(1); _Pragma("unroll")           \
    for (int ii = 0; ii < 4; ii++) { _Pragma("unroll")                        \
      for (int jj = 0; jj < 4; jj++)                                          \
        acc[ii][jj] = __builtin_amdgcn_mfma_f32_16x16x32_bf16(                \
            af[ii], bfr[jj], acc[ii][jj], 0, 0, 0);                           \
    }                                                                         \
    __builtin_amdgcn_s_setprio(0); } while (0)

template <int EPI>
__global__ __launch_bounds__(512, 2) void gemm_fp(
    const unsigned short* __restrict__ A, const unsigned short* __restrict__ B,
    float* __restrict__ Cf, long long sA, long long sB, long long sC,
    int K, int lda, int ldb, int ldc,
    unsigned short* __restrict__ u0, unsigned short* __restrict__ u1,
    unsigned short* __restrict__ u2,
    const float* __restrict__ f0, const float* __restrict__ f1,
    const float* __restrict__ f2,
    float* __restrict__ rsum, float scale)
{
  __shared__ unsigned short lds[3 * BUFE];  // 144 KiB

  const int t = threadIdx.x;
  const int rowBase = blockIdx.y * 256;
  const int colBase = blockIdx.x * 128;
  A += (long long)blockIdx.z * sA;
  B += (long long)blockIdx.z * sB;

  const int l = t & 63;
  const int w = t >> 6;              // 0..7
  const int wrow = (w >> 1) * 64;    // 4 M-waves
  const int wcol = (w & 1) * 64;     // 2 N-waves
  const int q = l >> 4;
  const int r16 = l & 15;

  // staging geometry: thread t covers row r0 = t>>3 (of a 64-row block),
  // slot t&7, global k-chunk = (t&7)^(r0&7) (pre-swizzled source).
  const int r0 = t >> 3;                        // 0..63
  const int goff = ((t & 7) ^ (r0 & 7)) << 3;

  f32x4 acc[4][4] = {};
  bf16x8 af[4], bfr[4];

  // prologue: tile0 -> buf0 (6 loads), tile1 -> buf1 (6 loads);
  // vmcnt(6) drains tile0 only, tile1 stays in flight.
  S64A(0, 0, 0); S64A(0, 1, 0); S64A(0, 2, 0); S64A(0, 3, 0);
  S64B(0, 0, 0); S64B(0, 1, 0);
  S64A(64, 0, BUFE); S64A(64, 1, BUFE); S64A(64, 2, BUFE); S64A(64, 3, BUFE);
  S64B(64, 0, BUFE); S64B(64, 1, BUFE);
  WAITV(6);
  BAR();

  int bo = 0, bn1 = BUFE, bn2 = 2 * BUFE;
  for (int kt = 0; kt < K; kt += 64) {
    const bool st = (kt + 128 < K);   // stage tile kt+128 into bn2
    // ---- phase ks0: reads + 3 stages; barrier; 16 MFMA; barrier
    LDA(bo, 0); LDB(bo, 0);
    if (st) { S64A(kt + 128, 0, bn2); S64A(kt + 128, 1, bn2); S64B(kt + 128, 0, bn2); }
    BAR();
    MMK();
    BAR();
    // ---- phase ks1: reads + 3 stages; barrier; 16 MFMA; vmcnt; barrier
    LDA(bo, 1); LDB(bo, 1);
    if (st) { S64A(kt + 128, 2, bn2); S64A(kt + 128, 3, bn2); S64B(kt + 128, 1, bn2); }
    BAR();
    MMK();
    if (st) { WAITV(6); } else { WAITV(0); }
    BAR();
    int tmp = bo; bo = bn1; bn1 = bn2; bn2 = tmp;
  }

  // epilogues: C frag layout row=(lane>>4)*4+r, col=lane&15 (m89/m91)
  if (EPI == 1) {
    unsigned short* p16 = u0 + (long long)blockIdx.z * sC;
    float* rs = rsum + (long long)blockIdx.z * 2048;
#pragma unroll
    for (int i = 0; i < 4; i++) {
#pragma unroll
      for (int r = 0; r < 4; r++) {
        int row = rowBase + wrow + i * 16 + q * 4 + r;
        float rowpart = 0.f;
#pragma unroll
        for (int j = 0; j < 4; j++) {
          int col = colBase + wcol + j * 16 + r16;
          float e = __expf(acc[i][j][r] * scale);
          p16[(size_t)row * ldc + col] = f2bf(e);
          rowpart += e;
        }
#pragma unroll
        for (int m = 1; m < 16; m <<= 1) rowpart += __shfl_xor(rowpart, m);
        if (r16 == 0) atomicAdd(rs + row, rowpart);
      }
    }
  } else if (EPI == 2) {
    const int seg = colBase >> 10;  // block-uniform (128-tile never straddles)
    if (seg < 2) {
      unsigned short* dst = seg ? u1 : u0;
      const float* bias = seg ? f1 : f0;
      const int cb = colBase & 1023;
#pragma unroll
      for (int i = 0; i < 4; i++) {
#pragma unroll
        for (int r = 0; r < 4; r++) {
          int row = rowBase + wrow + i * 16 + q * 4 + r;
#pragma unroll
          for (int j = 0; j < 4; j++) {
            int col = cb + wcol + j * 16 + r16;
            dst[(size_t)row * 1024 + col] = f2bf(acc[i][j][r] + bias[col]);
          }
        }
      }
    } else {
      const int ob = colBase - 2048;
#pragma unroll
      for (int i = 0; i < 4; i++) {
        int posBase = rowBase + wrow + i * 16 + q * 4;
        int b = posBase >> 11;
        int pos = posBase & 2047;
#pragma unroll
        for (int j = 0; j < 4; j++) {
          int o = ob + wcol + j * 16 + r16;
          float bias = f2[o];
          ushort4 pk;
          pk.x = f2bf(acc[i][j][0] + bias);
          pk.y = f2bf(acc[i][j][1] + bias);
          pk.z = f2bf(acc[i][j][2] + bias);
          pk.w = f2bf(acc[i][j][3] + bias);
          *(ushort4*)(u2 + ((size_t)((b << 10) + o) * 2048 + pos)) = pk;
        }
      }
    }
  } else {  // EPI == 3
    float* C = Cf + (long long)blockIdx.z * sC;
    const float* rs = rsum + (long long)blockIdx.z * 2048;
#pragma unroll
    for (int i = 0; i < 4; i++) {
#pragma unroll
      for (int r = 0; r < 4; r++) {
        int row = rowBase + wrow + i * 16 + q * 4 + r;
        float inv = 1.0f / rs[row];
#pragma unroll
        for (int j = 0; j < 4; j++) {
          int col = colBase + wcol + j * 16 + r16;
          C[(size_t)row * ldc + col] = acc[i][j][r] * inv;
        }
      }
    }
  }
}

// ---------- fp32 -> bf16 cast (vectorized) + rsum zero-fill ----------

__global__ __launch_bounds__(256) void cast_f32_to_bf16(
    const float* __restrict__ in, unsigned short* __restrict__ out, int n4,
    float* __restrict__ rzero, int nz4)
{
  int i = blockIdx.x * 256 + threadIdx.x;
  if (i < nz4) ((float4*)rzero)[i] = make_float4(0.f, 0.f, 0.f, 0.f);
  if (i >= n4) return;
  float4 v = ((const float4*)in)[i];
  ushort4 o;
  o.x = f2bf(v.x); o.y = f2bf(v.y); o.z = f2bf(v.z); o.w = f2bf(v.w);
  ((ushort4*)out)[i] = o;
}

// ---------- W transpose: WT[z][h, d] = bf16(W_z[d, h]), 1024x1024, z=0..2 ----------

__global__ __launch_bounds__(256) void wtrans(
    const float* __restrict__ Wq, const float* __restrict__ Wk,
    const float* __restrict__ Wv, unsigned short* __restrict__ WT)
{
  __shared__ float tile[32][33];
  const float* in = blockIdx.z == 0 ? Wq : (blockIdx.z == 1 ? Wk : Wv);
  unsigned short* out = WT + (size_t)blockIdx.z * 1024 * 1024;
  const int bc = blockIdx.x * 32;  // h
  const int br = blockIdx.y * 32;  // d
  const int tx = threadIdx.x;
  const int ty = threadIdx.y;
#pragma unroll
  for (int i = 0; i < 4; i++)
    tile[ty + i * 8][tx] = in[(size_t)(br + ty + i * 8) * 1024 + bc + tx];
  __syncthreads();
#pragma unroll
  for (int i = 0; i < 4; i++)
    out[(size_t)(bc + ty + i * 8) * 1024 + br + tx] = f2bf(tile[tx][ty + i * 8]);
}

// ---------- driver ----------

extern "C" void kernel_launch(void* const* d_in, const int* in_sizes, int n_in,
                              void* d_out, int out_size, void* d_ws, size_t ws_size,
                              hipStream_t stream) {
  (void)in_sizes; (void)n_in; (void)out_size;

  const float* x  = (const float*)d_in[0];
  const float* Wq = (const float*)d_in[1];
  const float* bq = (const float*)d_in[2];
  const float* Wk = (const float*)d_in[3];
  const float* bk = (const float*)d_in[4];
  const float* Wv = (const float*)d_in[5];
  const float* bv = (const float*)d_in[6];
  float* out = (float*)d_out;

  const int Nb = 4, L = 2048, D = 1024, H = 1024, O = 1024;
  const int M = Nb * L;      // 8192
  const int NQKV = 3 * H;    // 3072

  char* ws = (char*)d_ws;
  size_t off = 0;
  unsigned short* xb = (unsigned short*)(ws + off); off += (size_t)M * D * 2;
  unsigned short* qb = (unsigned short*)(ws + off); off += (size_t)M * H * 2;
  unsigned short* kb = (unsigned short*)(ws + off); off += (size_t)M * H * 2;
  unsigned short* vt = (unsigned short*)(ws + off); off += (size_t)M * O * 2;
  unsigned short* WT = (unsigned short*)(ws + off); off += (size_t)NQKV * D * 2;
  unsigned short* P  = (unsigned short*)(ws + off); off += (size_t)Nb * L * L * 2;
  float* rsum = (float*)(ws + off); off += (size_t)Nb * L * 4;
  if (ws_size < off) return;

  dim3 blk256(256);
  dim3 blk512(512);

  // x -> bf16, and zero the row-sum accumulator (ws is poisoned every call)
  cast_f32_to_bf16<<<(M * D / 4 + 255) / 256, blk256, 0, stream>>>(
      x, xb, M * D / 4, rsum, Nb * L / 4);

  // WT = concat(Wq^T, Wk^T, Wv^T) as bf16 [3072, 1024] (one launch, z=3)
  wtrans<<<dim3(32, 32, 3), dim3(32, 8), 0, stream>>>(Wq, Wk, Wv, WT);

  // fused projections: q -> qb, k -> kb, v -> vt (transposed), + biases
  // grid 24x32 = 768 blocks = 3.0 exact rounds, x-fastest (R5 locality: 79MB)
  gemm_fp<2><<<dim3(NQKV / 128, M / 256, 1), blk512, 0, stream>>>(
      xb, WT, nullptr, 0, 0, 0, D, D, D, 0,
      qb, kb, vt, bq, bk, bv, nullptr, 0.f);

  // QK + exp + row-sum atomics: P'[b] = exp(q k^T * scale)
  // grid 16x8x4 = 512 blocks = 2.0 exact rounds
  gemm_fp<1><<<dim3(L / 128, L / 256, Nb), blk512, 0, stream>>>(
      qb, kb, nullptr, (long long)L * H, (long long)L * H, (long long)L * L,
      H, H, H, L,
      P, nullptr, nullptr, nullptr, nullptr, nullptr,
      rsum, 0.022097086912079608f /* 1/sqrt(2048) */);

  // out[b] = (P'[b] @ vt[b]^T) / rsum
  // grid 8x8x4 = 256 blocks = 1.0 exact round
  gemm_fp<3><<<dim3(O / 128, L / 256, Nb), blk512, 0, stream>>>(
      P, vt, out, (long long)L * L, (long long)O * L, (long long)L * O,
      L, L, L, O,
      nullptr, nullptr, nullptr, nullptr, nullptr, nullptr,
      rsum, 0.f);
}

// Round 8
// 240.464 us; speedup vs baseline: 1.1079x; 1.0802x over previous
//
#include <hip/hip_runtime.h>
#include <hip/hip_bf16.h>

// ---------- helpers ----------

typedef __attribute__((ext_vector_type(8))) short bf16x8;
typedef __attribute__((ext_vector_type(4))) float f32x4;

#define AS_G(p) ((__attribute__((address_space(1))) void*)(p))
#define AS_L(p) ((__attribute__((address_space(3))) void*)(p))

__device__ __forceinline__ unsigned short f2bf(float f) {
  unsigned int u = __float_as_uint(f);
  unsigned int lsb = (u >> 16) & 1u;
  u += 0x7fffu + lsb;
  return (unsigned short)(u >> 16);
}

#define WAITV(n) asm volatile("s_waitcnt vmcnt(" #n ")" ::: "memory")
#define BAR() do { asm volatile("" ::: "memory");                             \
    __builtin_amdgcn_s_barrier();                                             \
    asm volatile("" ::: "memory"); } while (0)

// ---------- 128x128 2-region NT GEMM, counted vmcnt, 2 BLOCKS PER CU ----------
// R0-R7 post-mortem: every intra-block schedule variant hit MfmaUtil 27-31%.
// Arithmetic: per K-tile the LDS port needs ~1600 cyc (reads 131KB + DMA
// 48KB at 112 B/cyc/CU) and the MFMA pipe ~1241 cyc/SIMD; with ONE lockstep
// workgroup per CU they serialize (sum ~2840 ~= measured 3264). Fix (m114:
// independent waves overlap pipes): 128x128 tile, 256 thr = 4 waves (2M x
// 2N, per-wave 64x64 = same frag code), LDS 2 buf x 32KB = 64KB -> TWO
// blocks/CU with independent barrier groups; block A's LDS bursts overlap
// block B's MFMA bursts. Per-CU ideal: max(1714, 1241) vs serial 3264.
//
// A[m,k] lda, B[n,k] ldb, bf16, K-contiguous. BK=64, acc[4][4]/wave.
// Swizzle (0 SQ_LDS_BANK_CONFLICT all rounds): LDS row = 8 chunks of 8
// elems (16B); slot s of row r holds k-chunk s ^ (r&7); staging pre-swizzles
// the GLOBAL source so the LDS dest stays linear (global_load_lds req).
//
// 2-region K-tile (R5 TILE4 audit, resized): R1 = {all A frag-reads (both
// ks) + B jh0 reads; carry-stage B(t+1) -> OTHER buf; bar; MFMA cols 0-1;
// bar}. R2 = {B jh1 reads; lead-stage A(t+2) -> THIS buf; bar; MFMA cols
// 2-3; vmcnt(4); bar}. WAR: A rows of buf(t) die after R1 (lead is
// barrier-ordered); B jh0/jh1 rows die after R1/R2; other-buf carry targets
// buf(t+1) whose tenant t-1 was fully read by end of tile t-1. RAW: end of
// tile t-1's vmcnt(4) keeps only lead A(t+1); drains everything older ->
// buf(t) complete (loads finish oldest-first, m135). Steady-state in-flight
// never drains to 0 (m218). Prologue stages t0+t1 (16 loads), vmcnt(8).
// Per-element accumulation order: K ascending, ks0 then ks1, cols 0-1 then
// 2-3 -- identical to R5 -> bit-identical output.
//
// EPI=1: QK: P' = bf16(exp(acc*scale)) (unnormalized softmax numerator;
//        |acc*scale| small by construction) + fp32 atomic row-sum to rsum.
// EPI=2: proj split: col seg 0 -> qb (+bq), seg 1 -> kb (+bk), seg 2 -> vt
//        TRANSPOSED (+bv) as ushort4.
// EPI=3: PV: out fp32 = acc / rsum[row].

#define BUFE 16384  // elems per LDS buffer: A 8192 + B 8192 (32 KB)

// stage one 32-row block (1 global_load_lds per thread, 256thr x 16B = 4KB)
#define S32A(ktk, rb, bofs)                                                   \
  __builtin_amdgcn_global_load_lds(                                           \
      AS_G(A + (size_t)(rowBase + (rb) * 32 + r0) * lda + (ktk) + goff),      \
      AS_L(lds + (bofs) + (rb) * 2048 + t * 8), 16, 0, 0)

#define S32B(ktk, rb, bofs)                                                   \
  __builtin_amdgcn_global_load_lds(                                           \
      AS_G(B + (size_t)(colBase + (rb) * 32 + r0) * ldb + (ktk) + goff),      \
      AS_L(lds + (bofs) + 8192 + (rb) * 2048 + t * 8), 16, 0, 0)

// all A frag-reads for this wave (both K-halves): 8 x ds_read_b128
#define LDA4(bofs) do { _Pragma("unroll")                                     \
    for (int ks_ = 0; ks_ < 2; ks_++) { _Pragma("unroll")                     \
      for (int ii = 0; ii < 4; ii++) {                                        \
        int row_ = wrow + ii * 16 + r16;                                      \
        int slot_ = (ks_ * 4 + q) ^ (r16 & 7);                                \
        af[ks_][ii] = *(const bf16x8*)(lds + (bofs) + row_ * 64 + slot_ * 8); \
      } } } while (0)

// B frag-reads for col-half jh (both K-halves): 4 x ds_read_b128
#define LDB(jh, bofs) do { _Pragma("unroll")                                  \
    for (int ks_ = 0; ks_ < 2; ks_++) { _Pragma("unroll")                     \
      for (int jj = 0; jj < 2; jj++) {                                        \
        int row_ = wcol + ((jh) * 2 + jj) * 16 + r16;                         \
        int slot_ = (ks_ * 4 + q) ^ (r16 & 7);                                \
        bfr[ks_][(jh) * 2 + jj] =                                             \
            *(const bf16x8*)(lds + (bofs) + 8192 + row_ * 64 + slot_ * 8);    \
      } } } while (0)

#define MMQ(j0, j1) do { __builtin_amdgcn_s_setprio(1); _Pragma("unroll")     \
    for (int ks_ = 0; ks_ < 2; ks_++) { _Pragma("unroll")                     \
      for (int ii = 0; ii < 4; ii++) { _Pragma("unroll")                      \
        for (int jj = (j0); jj <= (j1); jj++)                                 \
          acc[ii][jj] = __builtin_amdgcn_mfma_f32_16x16x32_bf16(              \
              af[ks_][ii], bfr[ks_][jj], acc[ii][jj], 0, 0, 0);               \
      } }                                                                     \
    __builtin_amdgcn_s_setprio(0); } while (0)

#define TILE(ktc, bofs, obofs) do {                                           \
    /* R1: all-A + B jh0 reads; carry B(t+1) -> other buf */                  \
    LDA4(bofs); LDB(0, bofs);                                                 \
    if ((ktc) && (ktc) + 64 < K) {                                            \
      S32B((ktc) + 64, 0, obofs); S32B((ktc) + 64, 1, obofs);                 \
      S32B((ktc) + 64, 2, obofs); S32B((ktc) + 64, 3, obofs);                 \
    }                                                                         \
    BAR(); MMQ(0, 1); BAR();                                                  \
    /* R2: B jh1 reads; lead A(t+2) -> this buf; counted wait */              \
    LDB(1, bofs);                                                             \
    if ((ktc) + 128 < K) {                                                    \
      S32A((ktc) + 128, 0, bofs); S32A((ktc) + 128, 1, bofs);                 \
      S32A((ktc) + 128, 2, bofs); S32A((ktc) + 128, 3, bofs);                 \
    }                                                                         \
    BAR(); MMQ(2, 3);                                                         \
    if ((ktc) + 128 < K) { WAITV(4); } else { WAITV(0); }                     \
    BAR(); } while (0)

template <int EPI>
__global__ __launch_bounds__(256, 2) void gemm_db(
    const unsigned short* __restrict__ A, const unsigned short* __restrict__ B,
    float* __restrict__ Cf, long long sA, long long sB, long long sC,
    int K, int lda, int ldb, int ldc,
    unsigned short* __restrict__ u0, unsigned short* __restrict__ u1,
    unsigned short* __restrict__ u2,
    const float* __restrict__ f0, const float* __restrict__ f1,
    const float* __restrict__ f2,
    float* __restrict__ rsum, float scale)
{
  __shared__ unsigned short lds[2 * BUFE];  // 64 KiB -> 2 blocks/CU

  const int t = threadIdx.x;
  const int rowBase = blockIdx.y * 128;
  const int colBase = blockIdx.x * 128;
  A += (long long)blockIdx.z * sA;
  B += (long long)blockIdx.z * sB;

  const int l = t & 63;
  const int w = t >> 6;              // 0..3
  const int wrow = (w >> 1) * 64;    // 2 M-waves
  const int wcol = (w & 1) * 64;     // 2 N-waves
  const int q = l >> 4;
  const int r16 = l & 15;

  // staging geometry: thread t covers row r0 = t>>3 (of a 32-row block),
  // slot t&7, global k-chunk = (t&7)^(r0&7) (pre-swizzled source).
  const int r0 = t >> 3;                        // 0..31
  const int goff = ((t & 7) ^ (r0 & 7)) << 3;

  f32x4 acc[4][4] = {};
  bf16x8 af[2][4], bfr[2][4];

  // prologue: t0 -> buf0 (8 loads), t1 -> buf1 (8 loads); drain t0 only.
  S32A(0, 0, 0); S32A(0, 1, 0); S32A(0, 2, 0); S32A(0, 3, 0);
  S32B(0, 0, 0); S32B(0, 1, 0); S32B(0, 2, 0); S32B(0, 3, 0);
  S32A(64, 0, BUFE); S32A(64, 1, BUFE); S32A(64, 2, BUFE); S32A(64, 3, BUFE);
  S32B(64, 0, BUFE); S32B(64, 1, BUFE); S32B(64, 2, BUFE); S32B(64, 3, BUFE);
  WAITV(8);
  BAR();

  for (int kt = 0; kt < K; kt += 128) {   // K is a multiple of 128
    TILE(kt, 0, BUFE);
    TILE(kt + 64, BUFE, 0);
  }

  // epilogues: C frag layout row=(lane>>4)*4+r, col=lane&15 (m89/m91)
  if (EPI == 1) {
    unsigned short* p16 = u0 + (long long)blockIdx.z * sC;
    float* rs = rsum + (long long)blockIdx.z * 2048;
#pragma unroll
    for (int i = 0; i < 4; i++) {
#pragma unroll
      for (int r = 0; r < 4; r++) {
        int row = rowBase + wrow + i * 16 + q * 4 + r;
        float rowpart = 0.f;
#pragma unroll
        for (int j = 0; j < 4; j++) {
          int col = colBase + wcol + j * 16 + r16;
          float e = __expf(acc[i][j][r] * scale);
          p16[(size_t)row * ldc + col] = f2bf(e);
          rowpart += e;
        }
#pragma unroll
        for (int m = 1; m < 16; m <<= 1) rowpart += __shfl_xor(rowpart, m);
        if (r16 == 0) atomicAdd(rs + row, rowpart);
      }
    }
  } else if (EPI == 2) {
    const int seg = colBase >> 10;  // block-uniform (128-tile never straddles)
    if (seg < 2) {
      unsigned short* dst = seg ? u1 : u0;
      const float* bias = seg ? f1 : f0;
      const int cb = colBase & 1023;
#pragma unroll
      for (int i = 0; i < 4; i++) {
#pragma unroll
        for (int r = 0; r < 4; r++) {
          int row = rowBase + wrow + i * 16 + q * 4 + r;
#pragma unroll
          for (int j = 0; j < 4; j++) {
            int col = cb + wcol + j * 16 + r16;
            dst[(size_t)row * 1024 + col] = f2bf(acc[i][j][r] + bias[col]);
          }
        }
      }
    } else {
      const int ob = colBase - 2048;
#pragma unroll
      for (int i = 0; i < 4; i++) {
        int posBase = rowBase + wrow + i * 16 + q * 4;
        int b = posBase >> 11;
        int pos = posBase & 2047;
#pragma unroll
        for (int j = 0; j < 4; j++) {
          int o = ob + wcol + j * 16 + r16;
          float bias = f2[o];
          ushort4 pk;
          pk.x = f2bf(acc[i][j][0] + bias);
          pk.y = f2bf(acc[i][j][1] + bias);
          pk.z = f2bf(acc[i][j][2] + bias);
          pk.w = f2bf(acc[i][j][3] + bias);
          *(ushort4*)(u2 + ((size_t)((b << 10) + o) * 2048 + pos)) = pk;
        }
      }
    }
  } else {  // EPI == 3
    float* C = Cf + (long long)blockIdx.z * sC;
    const float* rs = rsum + (long long)blockIdx.z * 2048;
#pragma unroll
    for (int i = 0; i < 4; i++) {
#pragma unroll
      for (int r = 0; r < 4; r++) {
        int row = rowBase + wrow + i * 16 + q * 4 + r;
        float inv = 1.0f / rs[row];
#pragma unroll
        for (int j = 0; j < 4; j++) {
          int col = colBase + wcol + j * 16 + r16;
          C[(size_t)row * ldc + col] = acc[i][j][r] * inv;
        }
      }
    }
  }
}

// ---------- fp32 -> bf16 cast (vectorized) + rsum zero-fill ----------

__global__ __launch_bounds__(256) void cast_f32_to_bf16(
    const float* __restrict__ in, unsigned short* __restrict__ out, int n4,
    float* __restrict__ rzero, int nz4)
{
  int i = blockIdx.x * 256 + threadIdx.x;
  if (i < nz4) ((float4*)rzero)[i] = make_float4(0.f, 0.f, 0.f, 0.f);
  if (i >= n4) return;
  float4 v = ((const float4*)in)[i];
  ushort4 o;
  o.x = f2bf(v.x); o.y = f2bf(v.y); o.z = f2bf(v.z); o.w = f2bf(v.w);
  ((ushort4*)out)[i] = o;
}

// ---------- W transpose: WT[z][h, d] = bf16(W_z[d, h]), 1024x1024, z=0..2 ----------

__global__ __launch_bounds__(256) void wtrans(
    const float* __restrict__ Wq, const float* __restrict__ Wk,
    const float* __restrict__ Wv, unsigned short* __restrict__ WT)
{
  __shared__ float tile[32][33];
  const float* in = blockIdx.z == 0 ? Wq : (blockIdx.z == 1 ? Wk : Wv);
  unsigned short* out = WT + (size_t)blockIdx.z * 1024 * 1024;
  const int bc = blockIdx.x * 32;  // h
  const int br = blockIdx.y * 32;  // d
  const int tx = threadIdx.x;
  const int ty = threadIdx.y;
#pragma unroll
  for (int i = 0; i < 4; i++)
    tile[ty + i * 8][tx] = in[(size_t)(br + ty + i * 8) * 1024 + bc + tx];
  __syncthreads();
#pragma unroll
  for (int i = 0; i < 4; i++)
    out[(size_t)(bc + ty + i * 8) * 1024 + br + tx] = f2bf(tile[tx][ty + i * 8]);
}

// ---------- driver ----------

extern "C" void kernel_launch(void* const* d_in, const int* in_sizes, int n_in,
                              void* d_out, int out_size, void* d_ws, size_t ws_size,
                              hipStream_t stream) {
  (void)in_sizes; (void)n_in; (void)out_size;

  const float* x  = (const float*)d_in[0];
  const float* Wq = (const float*)d_in[1];
  const float* bq = (const float*)d_in[2];
  const float* Wk = (const float*)d_in[3];
  const float* bk = (const float*)d_in[4];
  const float* Wv = (const float*)d_in[5];
  const float* bv = (const float*)d_in[6];
  float* out = (float*)d_out;

  const int Nb = 4, L = 2048, D = 1024, H = 1024, O = 1024;
  const int M = Nb * L;      // 8192
  const int NQKV = 3 * H;    // 3072

  char* ws = (char*)d_ws;
  size_t off = 0;
  unsigned short* xb = (unsigned short*)(ws + off); off += (size_t)M * D * 2;
  unsigned short* qb = (unsigned short*)(ws + off); off += (size_t)M * H * 2;
  unsigned short* kb = (unsigned short*)(ws + off); off += (size_t)M * H * 2;
  unsigned short* vt = (unsigned short*)(ws + off); off += (size_t)M * O * 2;
  unsigned short* WT = (unsigned short*)(ws + off); off += (size_t)NQKV * D * 2;
  unsigned short* P  = (unsigned short*)(ws + off); off += (size_t)Nb * L * L * 2;
  float* rsum = (float*)(ws + off); off += (size_t)Nb * L * 4;
  if (ws_size < off) return;

  dim3 blk256(256);

  // x -> bf16, and zero the row-sum accumulator (ws is poisoned every call)
  cast_f32_to_bf16<<<(M * D / 4 + 255) / 256, blk256, 0, stream>>>(
      x, xb, M * D / 4, rsum, Nb * L / 4);

  // WT = concat(Wq^T, Wk^T, Wv^T) as bf16 [3072, 1024] (one launch, z=3)
  wtrans<<<dim3(32, 32, 3), dim3(32, 8), 0, stream>>>(Wq, Wk, Wv, WT);

  // fused projections: q -> qb, k -> kb, v -> vt (transposed), + biases
  // grid 24x64 = 1536 blocks = 3.0 exact dual-rounds (2 blocks/CU)
  gemm_db<2><<<dim3(NQKV / 128, M / 128, 1), blk256, 0, stream>>>(
      xb, WT, nullptr, 0, 0, 0, D, D, D, 0,
      qb, kb, vt, bq, bk, bv, nullptr, 0.f);

  // QK + exp + row-sum atomics: P'[b] = exp(q k^T * scale)
  // grid 16x16x4 = 1024 blocks = 2.0 exact dual-rounds
  gemm_db<1><<<dim3(L / 128, L / 128, Nb), blk256, 0, stream>>>(
      qb, kb, nullptr, (long long)L * H, (long long)L * H, (long long)L * L,
      H, H, H, L,
      P, nullptr, nullptr, nullptr, nullptr, nullptr,
      rsum, 0.022097086912079608f /* 1/sqrt(2048) */);

  // out[b] = (P'[b] @ vt[b]^T) / rsum
  // grid 8x16x4 = 512 blocks = 1.0 exact dual-round
  gemm_db<3><<<dim3(O / 128, L / 128, Nb), blk256, 0, stream>>>(
      P, vt, out, (long long)L * L, (long long)O * L, (long long)L * O,
      L, L, L, O,
      nullptr, nullptr, nullptr, nullptr, nullptr, nullptr,
      rsum, 0.f);
}

// Round 9
// 221.888 us; speedup vs baseline: 1.2006x; 1.0837x over previous
//
#include <hip/hip_runtime.h>
#include <hip/hip_bf16.h>

// ---------- helpers ----------

typedef __attribute__((ext_vector_type(8))) short bf16x8;
typedef __attribute__((ext_vector_type(4))) float f32x4;

#define AS_G(p) ((__attribute__((address_space(1))) void*)(p))
#define AS_L(p) ((__attribute__((address_space(3))) void*)(p))

__device__ __forceinline__ unsigned short f2bf(float f) {
  unsigned int u = __float_as_uint(f);
  unsigned int lsb = (u >> 16) & 1u;
  u += 0x7fffu + lsb;
  return (unsigned short)(u >> 16);
}

#define WAITV(n) asm volatile("s_waitcnt vmcnt(" #n ")" ::: "memory")
#define BAR() do { asm volatile("" ::: "memory");                             \
    __builtin_amdgcn_s_barrier();                                             \
    asm volatile("" ::: "memory"); } while (0)

// ---------- 128x128 2-region NT GEMM, counted vmcnt, 2 BLOCKS PER CU ----------
// R8 (validated: proj 65.4->59.8us, MfmaUtil 31->35.4): 128x128 tile, 256
// thr = 4 waves (2M x 2N, per-wave 64x64), LDS 2 buf x 32KB = 64KB -> TWO
// blocks/CU with independent barrier groups; block A's LDS bursts overlap
// block B's MFMA bursts (m114). Now ~LDS-port-bound: per tile-pair observed
// 2990 cyc vs port floor ~2048 (reads 64KB @85B/cyc + DMA 32KB @128B/cyc,
// x2 blocks) + MFMA 1241.
//
// R9 adds XCD-CHUNKED swizzle (T1): launch 1D, block id -> swz =
// (id%8)*(nwg/8) + id/8 (bijective, nwg%8==0), then decode x (fastest), y,
// z from swz. HW assigns launch-id n to XCD n%8, so each XCD receives a
// CONTIGUOUS run of the original x-fastest order: per-XCD working set drops
// from ~21 row-panels (5.4MB, thrashes 4MB L2) to 8 (~2MB resident). NOT
// the R6 mistake: R6 changed the per-block tile mapping (strided x) and
// destroyed panel sharing (FETCH 79->200MB); chunked swizzle preserves the
// neighborhood order exactly. Canary: FETCH_SIZE must stay ~76MB.
//
// A[m,k] lda, B[n,k] ldb, bf16, K-contiguous. BK=64, acc[4][4]/wave.
// Swizzle (0 SQ_LDS_BANK_CONFLICT all rounds): LDS row = 8 chunks of 8
// elems (16B); slot s of row r holds k-chunk s ^ (r&7); staging pre-swizzles
// the GLOBAL source so the LDS dest stays linear (global_load_lds req).
//
// 2-region K-tile (R5/R8 audit): R1 = {all A frag-reads (both ks) + B jh0
// reads; carry-stage B(t+1) -> OTHER buf; bar; MFMA cols 0-1; bar}. R2 =
// {B jh1 reads; lead-stage A(t+2) -> THIS buf; bar; MFMA cols 2-3;
// vmcnt(4); bar}. WAR: A rows of buf(t) die after R1 (lead is barrier-
// ordered); B jh0/jh1 rows die after R1/R2; carry targets buf(t+1) whose
// tenant t-1 was fully read by end of tile t-1. RAW: end of tile t-1's
// vmcnt(4) keeps only lead A(t+1); drains everything older -> buf(t)
// complete (loads finish oldest-first, m135). Never drains to 0 in steady
// state (m218). Prologue stages t0+t1 (16 loads), vmcnt(8). Per-element
// accumulation order identical to R5/R8 -> bit-identical output.
//
// EPI=1: QK: P' = bf16(exp(acc*scale)) (unnormalized softmax numerator;
//        |acc*scale| small by construction) + fp32 atomic row-sum to rsum.
// EPI=2: proj split: col seg 0 -> qb (+bq), seg 1 -> kb (+bk), seg 2 -> vt
//        TRANSPOSED (+bv) as ushort4.
// EPI=3: PV: out fp32 = acc / rsum[row].

#define BUFE 16384  // elems per LDS buffer: A 8192 + B 8192 (32 KB)

// stage one 32-row block (1 global_load_lds per thread, 256thr x 16B = 4KB)
#define S32A(ktk, rb, bofs)                                                   \
  __builtin_amdgcn_global_load_lds(                                           \
      AS_G(A + (size_t)(rowBase + (rb) * 32 + r0) * lda + (ktk) + goff),      \
      AS_L(lds + (bofs) + (rb) * 2048 + t * 8), 16, 0, 0)

#define S32B(ktk, rb, bofs)                                                   \
  __builtin_amdgcn_global_load_lds(                                           \
      AS_G(B + (size_t)(colBase + (rb) * 32 + r0) * ldb + (ktk) + goff),      \
      AS_L(lds + (bofs) + 8192 + (rb) * 2048 + t * 8), 16, 0, 0)

// all A frag-reads for this wave (both K-halves): 8 x ds_read_b128
#define LDA4(bofs) do { _Pragma("unroll")                                     \
    for (int ks_ = 0; ks_ < 2; ks_++) { _Pragma("unroll")                     \
      for (int ii = 0; ii < 4; ii++) {                                        \
        int row_ = wrow + ii * 16 + r16;                                      \
        int slot_ = (ks_ * 4 + q) ^ (r16 & 7);                                \
        af[ks_][ii] = *(const bf16x8*)(lds + (bofs) + row_ * 64 + slot_ * 8); \
      } } } while (0)

// B frag-reads for col-half jh (both K-halves): 4 x ds_read_b128
#define LDB(jh, bofs) do { _Pragma("unroll")                                  \
    for (int ks_ = 0; ks_ < 2; ks_++) { _Pragma("unroll")                     \
      for (int jj = 0; jj < 2; jj++) {                                        \
        int row_ = wcol + ((jh) * 2 + jj) * 16 + r16;                         \
        int slot_ = (ks_ * 4 + q) ^ (r16 & 7);                                \
        bfr[ks_][(jh) * 2 + jj] =                                             \
            *(const bf16x8*)(lds + (bofs) + 8192 + row_ * 64 + slot_ * 8);    \
      } } } while (0)

#define MMQ(j0, j1) do { __builtin_amdgcn_s_setprio(1); _Pragma("unroll")     \
    for (int ks_ = 0; ks_ < 2; ks_++) { _Pragma("unroll")                     \
      for (int ii = 0; ii < 4; ii++) { _Pragma("unroll")                      \
        for (int jj = (j0); jj <= (j1); jj++)                                 \
          acc[ii][jj] = __builtin_amdgcn_mfma_f32_16x16x32_bf16(              \
              af[ks_][ii], bfr[ks_][jj], acc[ii][jj], 0, 0, 0);               \
      } }                                                                     \
    __builtin_amdgcn_s_setprio(0); } while (0)

#define TILE(ktc, bofs, obofs) do {                                           \
    /* R1: all-A + B jh0 reads; carry B(t+1) -> other buf */                  \
    LDA4(bofs); LDB(0, bofs);                                                 \
    if ((ktc) && (ktc) + 64 < K) {                                            \
      S32B((ktc) + 64, 0, obofs); S32B((ktc) + 64, 1, obofs);                 \
      S32B((ktc) + 64, 2, obofs); S32B((ktc) + 64, 3, obofs);                 \
    }                                                                         \
    BAR(); MMQ(0, 1); BAR();                                                  \
    /* R2: B jh1 reads; lead A(t+2) -> this buf; counted wait */              \
    LDB(1, bofs);                                                             \
    if ((ktc) + 128 < K) {                                                    \
      S32A((ktc) + 128, 0, bofs); S32A((ktc) + 128, 1, bofs);                 \
      S32A((ktc) + 128, 2, bofs); S32A((ktc) + 128, 3, bofs);                 \
    }                                                                         \
    BAR(); MMQ(2, 3);                                                         \
    if ((ktc) + 128 < K) { WAITV(4); } else { WAITV(0); }                     \
    BAR(); } while (0)

template <int EPI>
__global__ __launch_bounds__(256, 2) void gemm_db(
    const unsigned short* __restrict__ A, const unsigned short* __restrict__ B,
    float* __restrict__ Cf, long long sA, long long sB, long long sC,
    int K, int lda, int ldb, int ldc,
    unsigned short* __restrict__ u0, unsigned short* __restrict__ u1,
    unsigned short* __restrict__ u2,
    const float* __restrict__ f0, const float* __restrict__ f1,
    const float* __restrict__ f2,
    float* __restrict__ rsum, float scale, int gx, int gy)
{
  __shared__ unsigned short lds[2 * BUFE];  // 64 KiB -> 2 blocks/CU

  const int t = threadIdx.x;

  // XCD-chunked bijective swizzle (launch is 1D, gridDim.x % 8 == 0):
  // XCD c (= launch id % 8) receives the contiguous run
  // [c*cpx, (c+1)*cpx) of the original x-fastest tile order.
  const int cpx = gridDim.x >> 3;
  const int swz = (blockIdx.x & 7) * cpx + (blockIdx.x >> 3);
  const int bx = swz % gx;
  const int byz = swz / gx;
  const int by = byz % gy;
  const int bz = byz / gy;

  const int rowBase = by * 128;
  const int colBase = bx * 128;
  A += (long long)bz * sA;
  B += (long long)bz * sB;

  const int l = t & 63;
  const int w = t >> 6;              // 0..3
  const int wrow = (w >> 1) * 64;    // 2 M-waves
  const int wcol = (w & 1) * 64;     // 2 N-waves
  const int q = l >> 4;
  const int r16 = l & 15;

  // staging geometry: thread t covers row r0 = t>>3 (of a 32-row block),
  // slot t&7, global k-chunk = (t&7)^(r0&7) (pre-swizzled source).
  const int r0 = t >> 3;                        // 0..31
  const int goff = ((t & 7) ^ (r0 & 7)) << 3;

  f32x4 acc[4][4] = {};
  bf16x8 af[2][4], bfr[2][4];

  // prologue: t0 -> buf0 (8 loads), t1 -> buf1 (8 loads); drain t0 only.
  S32A(0, 0, 0); S32A(0, 1, 0); S32A(0, 2, 0); S32A(0, 3, 0);
  S32B(0, 0, 0); S32B(0, 1, 0); S32B(0, 2, 0); S32B(0, 3, 0);
  S32A(64, 0, BUFE); S32A(64, 1, BUFE); S32A(64, 2, BUFE); S32A(64, 3, BUFE);
  S32B(64, 0, BUFE); S32B(64, 1, BUFE); S32B(64, 2, BUFE); S32B(64, 3, BUFE);
  WAITV(8);
  BAR();

  for (int kt = 0; kt < K; kt += 128) {   // K is a multiple of 128
    TILE(kt, 0, BUFE);
    TILE(kt + 64, BUFE, 0);
  }

  // epilogues: C frag layout row=(lane>>4)*4+r, col=lane&15 (m89/m91)
  if (EPI == 1) {
    unsigned short* p16 = u0 + (long long)bz * sC;
    float* rs = rsum + (long long)bz * 2048;
#pragma unroll
    for (int i = 0; i < 4; i++) {
#pragma unroll
      for (int r = 0; r < 4; r++) {
        int row = rowBase + wrow + i * 16 + q * 4 + r;
        float rowpart = 0.f;
#pragma unroll
        for (int j = 0; j < 4; j++) {
          int col = colBase + wcol + j * 16 + r16;
          float e = __expf(acc[i][j][r] * scale);
          p16[(size_t)row * ldc + col] = f2bf(e);
          rowpart += e;
        }
#pragma unroll
        for (int m = 1; m < 16; m <<= 1) rowpart += __shfl_xor(rowpart, m);
        if (r16 == 0) atomicAdd(rs + row, rowpart);
      }
    }
  } else if (EPI == 2) {
    const int seg = colBase >> 10;  // block-uniform (128-tile never straddles)
    if (seg < 2) {
      unsigned short* dst = seg ? u1 : u0;
      const float* bias = seg ? f1 : f0;
      const int cb = colBase & 1023;
#pragma unroll
      for (int i = 0; i < 4; i++) {
#pragma unroll
        for (int r = 0; r < 4; r++) {
          int row = rowBase + wrow + i * 16 + q * 4 + r;
#pragma unroll
          for (int j = 0; j < 4; j++) {
            int col = cb + wcol + j * 16 + r16;
            dst[(size_t)row * 1024 + col] = f2bf(acc[i][j][r] + bias[col]);
          }
        }
      }
    } else {
      const int ob = colBase - 2048;
#pragma unroll
      for (int i = 0; i < 4; i++) {
        int posBase = rowBase + wrow + i * 16 + q * 4;
        int b = posBase >> 11;
        int pos = posBase & 2047;
#pragma unroll
        for (int j = 0; j < 4; j++) {
          int o = ob + wcol + j * 16 + r16;
          float bias = f2[o];
          ushort4 pk;
          pk.x = f2bf(acc[i][j][0] + bias);
          pk.y = f2bf(acc[i][j][1] + bias);
          pk.z = f2bf(acc[i][j][2] + bias);
          pk.w = f2bf(acc[i][j][3] + bias);
          *(ushort4*)(u2 + ((size_t)((b << 10) + o) * 2048 + pos)) = pk;
        }
      }
    }
  } else {  // EPI == 3
    float* C = Cf + (long long)bz * sC;
    const float* rs = rsum + (long long)bz * 2048;
#pragma unroll
    for (int i = 0; i < 4; i++) {
#pragma unroll
      for (int r = 0; r < 4; r++) {
        int row = rowBase + wrow + i * 16 + q * 4 + r;
        float inv = 1.0f / rs[row];
#pragma unroll
        for (int j = 0; j < 4; j++) {
          int col = colBase + wcol + j * 16 + r16;
          C[(size_t)row * ldc + col] = acc[i][j][r] * inv;
        }
      }
    }
  }
}

// ---------- fused prep: cast x->bf16 + rsum zero + W transpose (one launch) ----------
// blocks [0, 8192): cast 4 floats each (8192*256*4 = 8M = M*D elems) +
//                   zero rsum float4s.
// blocks [8192, 11264): wtrans, b-8192 -> (z, by, bx) with 32x8 tile logic.

__global__ __launch_bounds__(256) void prep(
    const float* __restrict__ in, unsigned short* __restrict__ out,
    float* __restrict__ rzero, int nz4,
    const float* __restrict__ Wq, const float* __restrict__ Wk,
    const float* __restrict__ Wv, unsigned short* __restrict__ WT)
{
  __shared__ float tile[32][33];
  const int bid = blockIdx.x;
  const int t = threadIdx.x;
  if (bid < 8192) {
    int i = bid * 256 + t;
    if (i < nz4) ((float4*)rzero)[i] = make_float4(0.f, 0.f, 0.f, 0.f);
    float4 v = ((const float4*)in)[i];
    ushort4 o;
    o.x = f2bf(v.x); o.y = f2bf(v.y); o.z = f2bf(v.z); o.w = f2bf(v.w);
    ((ushort4*)out)[i] = o;
  } else {
    const int b = bid - 8192;
    const int z = b >> 10;            // 0..2
    const int by = (b & 1023) >> 5;   // 0..31 (d block)
    const int bx = b & 31;            // 0..31 (h block)
    const float* src = z == 0 ? Wq : (z == 1 ? Wk : Wv);
    unsigned short* dst = WT + (size_t)z * 1024 * 1024;
    const int bc = bx * 32;  // h
    const int br = by * 32;  // d
    const int tx = t & 31;
    const int ty = t >> 5;   // 0..7
#pragma unroll
    for (int i = 0; i < 4; i++)
      tile[ty + i * 8][tx] = src[(size_t)(br + ty + i * 8) * 1024 + bc + tx];
    __syncthreads();
#pragma unroll
    for (int i = 0; i < 4; i++)
      dst[(size_t)(bc + ty + i * 8) * 1024 + br + tx] = f2bf(tile[tx][ty + i * 8]);
  }
}

// ---------- driver ----------

extern "C" void kernel_launch(void* const* d_in, const int* in_sizes, int n_in,
                              void* d_out, int out_size, void* d_ws, size_t ws_size,
                              hipStream_t stream) {
  (void)in_sizes; (void)n_in; (void)out_size;

  const float* x  = (const float*)d_in[0];
  const float* Wq = (const float*)d_in[1];
  const float* bq = (const float*)d_in[2];
  const float* Wk = (const float*)d_in[3];
  const float* bk = (const float*)d_in[4];
  const float* Wv = (const float*)d_in[5];
  const float* bv = (const float*)d_in[6];
  float* out = (float*)d_out;

  const int Nb = 4, L = 2048, D = 1024, H = 1024, O = 1024;
  const int M = Nb * L;      // 8192
  const int NQKV = 3 * H;    // 3072

  char* ws = (char*)d_ws;
  size_t off = 0;
  unsigned short* xb = (unsigned short*)(ws + off); off += (size_t)M * D * 2;
  unsigned short* qb = (unsigned short*)(ws + off); off += (size_t)M * H * 2;
  unsigned short* kb = (unsigned short*)(ws + off); off += (size_t)M * H * 2;
  unsigned short* vt = (unsigned short*)(ws + off); off += (size_t)M * O * 2;
  unsigned short* WT = (unsigned short*)(ws + off); off += (size_t)NQKV * D * 2;
  unsigned short* P  = (unsigned short*)(ws + off); off += (size_t)Nb * L * L * 2;
  float* rsum = (float*)(ws + off); off += (size_t)Nb * L * 4;
  if (ws_size < off) return;

  dim3 blk256(256);

  // fused prep: x -> bf16, rsum zero (ws poisoned every call), W transposes
  prep<<<dim3(8192 + 3072), blk256, 0, stream>>>(
      x, xb, rsum, Nb * L / 4, Wq, Wk, Wv, WT);

  // fused projections: q -> qb, k -> kb, v -> vt (transposed), + biases
  // 1536 blocks = 3.0 exact dual-rounds (2 blocks/CU), XCD-chunked swizzle
  gemm_db<2><<<dim3(1536), blk256, 0, stream>>>(
      xb, WT, nullptr, 0, 0, 0, D, D, D, 0,
      qb, kb, vt, bq, bk, bv, nullptr, 0.f, 24, 64);

  // QK + exp + row-sum atomics: P'[b] = exp(q k^T * scale)
  // 1024 blocks = 2.0 exact dual-rounds
  gemm_db<1><<<dim3(1024), blk256, 0, stream>>>(
      qb, kb, nullptr, (long long)L * H, (long long)L * H, (long long)L * L,
      H, H, H, L,
      P, nullptr, nullptr, nullptr, nullptr, nullptr,
      rsum, 0.022097086912079608f /* 1/sqrt(2048) */, 16, 16);

  // out[b] = (P'[b] @ vt[b]^T) / rsum
  // 512 blocks = 1.0 exact dual-round
  gemm_db<3><<<dim3(512), blk256, 0, stream>>>(
      P, vt, out, (long long)L * L, (long long)O * L, (long long)L * O,
      L, L, L, O,
      nullptr, nullptr, nullptr, nullptr, nullptr, nullptr,
      rsum, 0.f, 8, 16);
}